// Round 1
// baseline (4582.668 us; speedup 1.0000x reference)
//
#include <hip/hip_runtime.h>
#include <hip/hip_bf16.h>

#define HH 224
#define WW 224

// d_out layout (floats): feats[32*128] | final_boxes[32*100*4] | final_scores[32*100] | keep[32*100]
#define OUT_FEATS  0
#define OUT_BOXES  4096
#define OUT_SCORES 16896
#define OUT_KEEP   20096

static __device__ __forceinline__ float bf2f(unsigned int u16bits) {
    union { unsigned int i; float f; } v;
    v.i = u16bits << 16;
    return v.f;
}

// ---------------- conv1: (32,3,224,224) fp32 -> relu -> h1 (32,64,224,224) bf16 ----------------
__global__ __launch_bounds__(256) void conv1_kernel(const float* __restrict__ x,
                                                    const float* __restrict__ w1,
                                                    const float* __restrict__ b1,
                                                    __hip_bfloat16* __restrict__ h1)
{
    const int tx = threadIdx.x & 15, ty = threadIdx.x >> 4;
    const int x0 = blockIdx.x * 16, y0 = blockIdx.y * 16, b = blockIdx.z;

    __shared__ float patch[3 * 18 * 18];
    for (int e = threadIdx.x; e < 3 * 18 * 18; e += 256) {
        int ic = e / 324; int rem = e - ic * 324;
        int r = rem / 18; int c = rem - r * 18;
        int gy = y0 + r - 1, gx = x0 + c - 1;
        float v = 0.f;
        if (gy >= 0 && gy < HH && gx >= 0 && gx < WW)
            v = x[((b * 3 + ic) * HH + gy) * WW + gx];
        patch[e] = v;
    }
    __syncthreads();

    float in[27];
#pragma unroll
    for (int ic = 0; ic < 3; ic++)
#pragma unroll
        for (int r = 0; r < 3; r++)
#pragma unroll
            for (int c = 0; c < 3; c++)
                in[ic * 9 + r * 3 + c] = patch[(ic * 18 + ty + r) * 18 + tx + c];

    const int out_y = y0 + ty, out_x = x0 + tx;
    unsigned short* h1u = (unsigned short*)h1;
    for (int oc = 0; oc < 64; oc++) {
        float acc = b1[oc];
#pragma unroll
        for (int k = 0; k < 27; k++) acc = fmaf(in[k], w1[oc * 27 + k], acc);
        acc = fmaxf(acc, 0.f);
        __hip_bfloat16 hb = __float2bfloat16(acc);
        h1u[((b * 64 + oc) * HH + out_y) * WW + out_x] = *(unsigned short*)&hb;
    }
}

// ---------------- conv2 + fused mean partials ----------------
// tile: 32 wide x 16 high; 256 threads; thread = 2 px (x) * 8 oc
// grid: (ocb=16, tile=98, b=32)   partial[(b*128+oc)*98 + tile]
__global__ __launch_bounds__(256) void conv2_kernel(const __hip_bfloat16* __restrict__ h1,
                                                    const float* __restrict__ w2,
                                                    const float* __restrict__ b2,
                                                    float* __restrict__ partial)
{
    const int ocb = blockIdx.x;     // 0..15
    const int tile = blockIdx.y;    // 0..97
    const int b = blockIdx.z;
    const int tile_x = tile % 7, tile_y = tile / 7;
    const int x0 = tile_x * 32, y0 = tile_y * 16;
    const int tx = threadIdx.x & 15, ty = threadIdx.x >> 4;

    __shared__ unsigned short patch[16 * 18 * 36]; // [ic][row 18][col padded 36]
    const unsigned short* h1u = (const unsigned short*)h1;

    float acc[8][2];
#pragma unroll
    for (int o = 0; o < 8; o++) { acc[o][0] = 0.f; acc[o][1] = 0.f; }

    for (int ic0 = 0; ic0 < 64; ic0 += 16) {
        __syncthreads();
        for (int e = threadIdx.x; e < 16 * 18 * 34; e += 256) {
            int ic = e / 612; int rem = e - ic * 612;
            int r = rem / 34; int c = rem - r * 34;
            int gy = y0 + r - 1, gx = x0 + c - 1;
            unsigned short v = 0;
            if (gy >= 0 && gy < HH && gx >= 0 && gx < WW)
                v = h1u[((b * 64 + ic0 + ic) * HH + gy) * WW + gx];
            patch[(ic * 18 + r) * 36 + c] = v;
        }
        __syncthreads();

#pragma unroll 4
        for (int ic = 0; ic < 16; ic++) {
            float inr[3][4];
#pragma unroll
            for (int r = 0; r < 3; r++) {
                const unsigned int* p32 =
                    (const unsigned int*)&patch[(ic * 18 + ty + r) * 36 + 2 * tx];
                unsigned int a = p32[0], bq = p32[1];
                inr[r][0] = bf2f(a & 0xffffu);
                inr[r][1] = bf2f(a >> 16);
                inr[r][2] = bf2f(bq & 0xffffu);
                inr[r][3] = bf2f(bq >> 16);
            }
            const float* wp = &w2[(ocb * 8 * 64 + (ic0 + ic)) * 9];
#pragma unroll
            for (int o = 0; o < 8; o++) {
                const float* w = wp + o * 64 * 9;
#pragma unroll
                for (int r = 0; r < 3; r++)
#pragma unroll
                    for (int c = 0; c < 3; c++) {
                        float wv = w[r * 3 + c];
                        acc[o][0] = fmaf(inr[r][c], wv, acc[o][0]);
                        acc[o][1] = fmaf(inr[r][c + 1], wv, acc[o][1]);
                    }
            }
        }
    }

    // epilogue: bias + relu + block-sum per oc (deterministic partials, no atomics)
    __shared__ float red[4][8];
    const int lane = threadIdx.x & 63, wid = threadIdx.x >> 6;
#pragma unroll
    for (int o = 0; o < 8; o++) {
        float bias = b2[ocb * 8 + o];
        float v = fmaxf(acc[o][0] + bias, 0.f) + fmaxf(acc[o][1] + bias, 0.f);
#pragma unroll
        for (int m = 32; m >= 1; m >>= 1) v += __shfl_xor(v, m, 64);
        if (lane == 0) red[wid][o] = v;
    }
    __syncthreads();
    if (threadIdx.x < 8) {
        float s = red[0][threadIdx.x] + red[1][threadIdx.x] +
                  red[2][threadIdx.x] + red[3][threadIdx.x];
        partial[((size_t)(b * 128 + ocb * 8 + threadIdx.x)) * 98 + tile] = s;
    }
}

// ---------------- feats reduce: 98 partials -> mean ----------------
__global__ void feats_reduce(const float* __restrict__ partial, float* __restrict__ out)
{
    int t = blockIdx.x * 256 + threadIdx.x;
    if (t >= 32 * 128) return;
    float s = 0.f;
    for (int k = 0; k < 98; k++) s += partial[(size_t)t * 98 + k];
    out[t] = s * (1.f / 50176.f);
}

// ---------------- NMS: one block per batch ----------------
__global__ __launch_bounds__(128) void nms_kernel(const float* __restrict__ boxes,
                                                  const float* __restrict__ scores,
                                                  float* __restrict__ out)
{
    const int b = blockIdx.x;
    const int tid = threadIdx.x;
    __shared__ float rs[100];
    __shared__ float bx1[100], by1[100], bx2[100], by2[100];
    __shared__ float ss[100], sx1[100], sy1[100], sx2[100], sy2[100], sarea[100];
    __shared__ int keep_s[100];

    if (tid < 100) {
        rs[tid] = scores[b * 100 + tid];
        bx1[tid] = boxes[(b * 100 + tid) * 4 + 0];
        by1[tid] = boxes[(b * 100 + tid) * 4 + 1];
        bx2[tid] = boxes[(b * 100 + tid) * 4 + 2];
        by2[tid] = boxes[(b * 100 + tid) * 4 + 3];
    }
    __syncthreads();
    if (tid < 100) {
        float s = rs[tid];
        int r = 0;
        for (int j = 0; j < 100; j++) {
            float sj = rs[j];
            r += (sj > s) || (sj == s && j < tid);  // stable descending rank
        }
        ss[r] = s; sx1[r] = bx1[tid]; sy1[r] = by1[tid];
        sx2[r] = bx2[tid]; sy2[r] = by2[tid];
        keep_s[tid] = 1;
    }
    __syncthreads();
    if (tid < 100)
        sarea[tid] = fmaxf(sx2[tid] - sx1[tid], 0.f) * fmaxf(sy2[tid] - sy1[tid], 0.f);
    __syncthreads();

    for (int i = 0; i < 99; i++) {
        if (keep_s[i] && tid > i && tid < 100) {
            float xx1 = fmaxf(sx1[i], sx1[tid]);
            float yy1 = fmaxf(sy1[i], sy1[tid]);
            float xx2 = fminf(sx2[i], sx2[tid]);
            float yy2 = fminf(sy2[i], sy2[tid]);
            float inter = fmaxf(xx2 - xx1, 0.f) * fmaxf(yy2 - yy1, 0.f);
            float iou = inter / (sarea[i] + sarea[tid] - inter + 1e-9f);
            if (iou > 0.5f) keep_s[tid] = 0;
        }
        __syncthreads();
    }

    if (tid < 100) {
        int k = keep_s[tid];
        int gi = b * 100 + tid;
        out[OUT_BOXES + gi * 4 + 0] = k ? sx1[tid] : 0.f;
        out[OUT_BOXES + gi * 4 + 1] = k ? sy1[tid] : 0.f;
        out[OUT_BOXES + gi * 4 + 2] = k ? sx2[tid] : 0.f;
        out[OUT_BOXES + gi * 4 + 3] = k ? sy2[tid] : 0.f;
        out[OUT_SCORES + gi] = k ? ss[tid] : 0.f;
        out[OUT_KEEP + gi] = k ? 1.f : 0.f;
    }
}

extern "C" void kernel_launch(void* const* d_in, const int* in_sizes, int n_in,
                              void* d_out, int out_size, void* d_ws, size_t ws_size,
                              hipStream_t stream)
{
    const float* x      = (const float*)d_in[0];
    const float* boxes  = (const float*)d_in[1];
    const float* scores = (const float*)d_in[2];
    const float* w1     = (const float*)d_in[3];
    const float* b1     = (const float*)d_in[4];
    const float* w2     = (const float*)d_in[5];
    const float* b2     = (const float*)d_in[6];
    float* out = (float*)d_out;

    __hip_bfloat16* h1 = (__hip_bfloat16*)d_ws;                       // 32*64*224*224 bf16 = 205.5 MB
    float* partial = (float*)((char*)d_ws + (size_t)32 * 64 * 224 * 224 * 2); // 32*128*98 f32 = 1.6 MB

    conv1_kernel<<<dim3(14, 14, 32), 256, 0, stream>>>(x, w1, b1, h1);
    conv2_kernel<<<dim3(16, 98, 32), 256, 0, stream>>>(h1, w2, b2, partial);
    feats_reduce<<<16, 256, 0, stream>>>(partial, out + OUT_FEATS);
    nms_kernel<<<32, 128, 0, stream>>>(boxes, scores, out);
}

// Round 2
// 668.996 us; speedup vs baseline: 6.8501x; 6.8501x over previous
//
#include <hip/hip_runtime.h>
#include <hip/hip_bf16.h>

#define HH 224
#define WW 224

// d_out layout (floats): feats[32*128] | final_boxes[32*100*4] | final_scores[32*100] | keep[32*100]
#define OUT_FEATS  0
#define OUT_BOXES  4096
#define OUT_SCORES 16896
#define OUT_KEEP   20096

typedef __attribute__((ext_vector_type(8))) short short8;
typedef __attribute__((ext_vector_type(4))) float f32x4;
typedef __attribute__((ext_vector_type(4))) unsigned int u32x4;

static __device__ __forceinline__ unsigned short f2bf(float f) {
    __hip_bfloat16 h = __float2bfloat16(f);
    return *(unsigned short*)&h;
}

// ---------------- w2 (128,64,3,3) fp32 -> bf16 [tap][oc][ic] ----------------
__global__ void w2_convert(const float* __restrict__ w2, unsigned short* __restrict__ w2bf)
{
    int t = blockIdx.x * 256 + threadIdx.x;
    if (t >= 9 * 128 * 64) return;
    int tap = t >> 13;            // t / 8192
    int rem = t & 8191;
    int oc = rem >> 6, ic = rem & 63;
    w2bf[t] = f2bf(w2[(oc * 64 + ic) * 9 + tap]);
}

// ---------------- conv1: (8,3,224,224) fp32 -> relu -> h1 slice NHWC bf16 ----------------
__global__ __launch_bounds__(256) void conv1_kernel(const float* __restrict__ x,
                                                    const float* __restrict__ w1,
                                                    const float* __restrict__ b1,
                                                    unsigned short* __restrict__ h1)
{
    const int tx = threadIdx.x & 15, ty = threadIdx.x >> 4;
    const int x0 = blockIdx.x * 16, y0 = blockIdx.y * 16, b = blockIdx.z;

    __shared__ float patch[3 * 18 * 18];
    for (int e = threadIdx.x; e < 3 * 18 * 18; e += 256) {
        int ic = e / 324; int rem = e - ic * 324;
        int r = rem / 18; int c = rem - r * 18;
        int gy = y0 + r - 1, gx = x0 + c - 1;
        float v = 0.f;
        if (gy >= 0 && gy < HH && gx >= 0 && gx < WW)
            v = x[((b * 3 + ic) * HH + gy) * WW + gx];
        patch[e] = v;
    }
    __syncthreads();

    float in[27];
#pragma unroll
    for (int ic = 0; ic < 3; ic++)
#pragma unroll
        for (int r = 0; r < 3; r++)
#pragma unroll
            for (int c = 0; c < 3; c++)
                in[ic * 9 + r * 3 + c] = patch[(ic * 18 + ty + r) * 18 + tx + c];

    const int out_y = y0 + ty, out_x = x0 + tx;
    unsigned short* dst = h1 + (((size_t)b * HH + out_y) * WW + out_x) * 64;

#pragma unroll
    for (int g = 0; g < 8; g++) {
        float a[8];
#pragma unroll
        for (int o = 0; o < 8; o++) {
            int oc = g * 8 + o;
            float acc = b1[oc];
#pragma unroll
            for (int k = 0; k < 27; k++) acc = fmaf(in[k], w1[oc * 27 + k], acc);
            a[o] = fmaxf(acc, 0.f);
        }
        u32x4 pk;
        pk.x = (unsigned int)f2bf(a[0]) | ((unsigned int)f2bf(a[1]) << 16);
        pk.y = (unsigned int)f2bf(a[2]) | ((unsigned int)f2bf(a[3]) << 16);
        pk.z = (unsigned int)f2bf(a[4]) | ((unsigned int)f2bf(a[5]) << 16);
        pk.w = (unsigned int)f2bf(a[6]) | ((unsigned int)f2bf(a[7]) << 16);
        *(u32x4*)(dst + g * 8) = pk;
    }
}

// ---------------- conv2 MFMA implicit GEMM + fused relu/mean partials ----------------
// block: 256 thr = 4 waves. Output tile: 64 px (4 rows x 16 cols) x 128 oc.
// wave w: all 64 px x 32 oc (oc base w*32). K = 9 taps x 64 ic.
// grid: (14 xt, 56 yt, 8 b_local)
__global__ __launch_bounds__(256) void conv2_kernel(const unsigned short* __restrict__ h1,
                                                    const unsigned short* __restrict__ w2bf,
                                                    const float* __restrict__ b2,
                                                    float* __restrict__ partial,
                                                    int bglobal_base)
{
    const int xt = blockIdx.x, yt = blockIdx.y, bl = blockIdx.z;
    const int x0 = xt * 16, y0 = yt * 4;
    const int tid = threadIdx.x;

    __shared__ short halo[6 * 18 * 64]; // [pos=row*18+col][ic], 16B chunks XOR-swizzled

    const unsigned short* hb = h1 + (size_t)bl * HH * WW * 64;
    for (int i = tid; i < 864; i += 256) {
        int pos = i >> 3, q = i & 7;
        int row = pos / 18, col = pos - row * 18;
        int gy = y0 + row - 1, gx = x0 + col - 1;
        u32x4 v = {0, 0, 0, 0};
        if (gy >= 0 && gy < HH && gx >= 0 && gx < WW)
            v = *(const u32x4*)(hb + ((gy * WW + gx) * 64 + q * 8));
        int byte = (pos * 128 + q * 16) ^ ((pos & 7) << 4);
        *(u32x4*)((char*)halo + byte) = v;
    }
    __syncthreads();

    const int lane = tid & 63, wv = tid >> 6;
    const int l15 = lane & 15, lq = lane >> 4;

    f32x4 acc[4][2];
#pragma unroll
    for (int mf = 0; mf < 4; mf++) {
        acc[mf][0] = (f32x4){0.f, 0.f, 0.f, 0.f};
        acc[mf][1] = (f32x4){0.f, 0.f, 0.f, 0.f};
    }

    // B frag base: lane reads w2bf[tap][oc = wvbase + nf*16 + l15][ic = kk*32 + lq*8 + j]
    const unsigned short* wb = w2bf + (wv * 32 + l15) * 64 + lq * 8;

#pragma unroll
    for (int dy = 0; dy < 3; dy++) {
#pragma unroll
        for (int dx = 0; dx < 3; dx++) {
            const int pbase = dy * 18 + l15 + dx;
            const int wofs = (dy * 3 + dx) * 8192;
#pragma unroll
            for (int kk = 0; kk < 2; kk++) {
                short8 b0 = *(const short8*)(wb + wofs + kk * 32);
                short8 b1 = *(const short8*)(wb + wofs + 1024 + kk * 32);
                short8 a[4];
#pragma unroll
                for (int mf = 0; mf < 4; mf++) {
                    int pos = pbase + mf * 18;
                    int byte = (pos * 128 + (kk * 4 + lq) * 16) ^ ((pos & 7) << 4);
                    a[mf] = *(const short8*)((const char*)halo + byte);
                }
#pragma unroll
                for (int mf = 0; mf < 4; mf++) {
                    acc[mf][0] = __builtin_amdgcn_mfma_f32_16x16x32_bf16(a[mf], b0, acc[mf][0], 0, 0, 0);
                    acc[mf][1] = __builtin_amdgcn_mfma_f32_16x16x32_bf16(a[mf], b1, acc[mf][1], 0, 0, 0);
                }
            }
        }
    }

    // epilogue: bias + relu + sum over the 64 px; C layout: col(oc)=l15, row(px)=lq*4+j
    float bias0 = b2[wv * 32 + l15];
    float bias1 = b2[wv * 32 + 16 + l15];
    float s0 = 0.f, s1 = 0.f;
#pragma unroll
    for (int mf = 0; mf < 4; mf++)
#pragma unroll
        for (int j = 0; j < 4; j++) {
            s0 += fmaxf(acc[mf][0][j] + bias0, 0.f);
            s1 += fmaxf(acc[mf][1][j] + bias1, 0.f);
        }
    s0 += __shfl_xor(s0, 16, 64); s0 += __shfl_xor(s0, 32, 64);
    s1 += __shfl_xor(s1, 16, 64); s1 += __shfl_xor(s1, 32, 64);

    if (lq == 0) {
        int bg = bglobal_base + bl;
        int tile = yt * 14 + xt;
        partial[((size_t)bg * 128 + wv * 32 + l15) * 784 + tile] = s0;
        partial[((size_t)bg * 128 + wv * 32 + 16 + l15) * 784 + tile] = s1;
    }
}

// ---------------- feats: sum 784 tile-partials -> mean ----------------
__global__ void feats_reduce(const float* __restrict__ partial, float* __restrict__ out)
{
    int t = blockIdx.x;           // 0..4095 = b*128+oc
    int lane = threadIdx.x;       // 64
    float s = 0.f;
    for (int k = lane; k < 784; k += 64) s += partial[(size_t)t * 784 + k];
#pragma unroll
    for (int m = 32; m >= 1; m >>= 1) s += __shfl_xor(s, m, 64);
    if (lane == 0) out[t] = s * (1.f / 50176.f);
}

// ---------------- NMS: one block per batch (exact reference semantics) ----------------
__global__ __launch_bounds__(128) void nms_kernel(const float* __restrict__ boxes,
                                                  const float* __restrict__ scores,
                                                  float* __restrict__ out)
{
    const int b = blockIdx.x;
    const int tid = threadIdx.x;
    __shared__ float rs[100];
    __shared__ float bx1[100], by1[100], bx2[100], by2[100];
    __shared__ float ss[100], sx1[100], sy1[100], sx2[100], sy2[100], sarea[100];
    __shared__ int keep_s[100];

    if (tid < 100) {
        rs[tid] = scores[b * 100 + tid];
        bx1[tid] = boxes[(b * 100 + tid) * 4 + 0];
        by1[tid] = boxes[(b * 100 + tid) * 4 + 1];
        bx2[tid] = boxes[(b * 100 + tid) * 4 + 2];
        by2[tid] = boxes[(b * 100 + tid) * 4 + 3];
    }
    __syncthreads();
    if (tid < 100) {
        float s = rs[tid];
        int r = 0;
        for (int j = 0; j < 100; j++) {
            float sj = rs[j];
            r += (sj > s) || (sj == s && j < tid);  // stable descending rank
        }
        ss[r] = s; sx1[r] = bx1[tid]; sy1[r] = by1[tid];
        sx2[r] = bx2[tid]; sy2[r] = by2[tid];
        keep_s[tid] = 1;
    }
    __syncthreads();
    if (tid < 100)
        sarea[tid] = fmaxf(sx2[tid] - sx1[tid], 0.f) * fmaxf(sy2[tid] - sy1[tid], 0.f);
    __syncthreads();

    for (int i = 0; i < 99; i++) {
        if (keep_s[i] && tid > i && tid < 100) {
            float xx1 = fmaxf(sx1[i], sx1[tid]);
            float yy1 = fmaxf(sy1[i], sy1[tid]);
            float xx2 = fminf(sx2[i], sx2[tid]);
            float yy2 = fminf(sy2[i], sy2[tid]);
            float inter = fmaxf(xx2 - xx1, 0.f) * fmaxf(yy2 - yy1, 0.f);
            float iou = inter / (sarea[i] + sarea[tid] - inter + 1e-9f);
            if (iou > 0.5f) keep_s[tid] = 0;
        }
        __syncthreads();
    }

    if (tid < 100) {
        int k = keep_s[tid];
        int gi = b * 100 + tid;
        out[OUT_BOXES + gi * 4 + 0] = k ? sx1[tid] : 0.f;
        out[OUT_BOXES + gi * 4 + 1] = k ? sy1[tid] : 0.f;
        out[OUT_BOXES + gi * 4 + 2] = k ? sx2[tid] : 0.f;
        out[OUT_BOXES + gi * 4 + 3] = k ? sy2[tid] : 0.f;
        out[OUT_SCORES + gi] = k ? ss[tid] : 0.f;
        out[OUT_KEEP + gi] = k ? 1.f : 0.f;
    }
}

extern "C" void kernel_launch(void* const* d_in, const int* in_sizes, int n_in,
                              void* d_out, int out_size, void* d_ws, size_t ws_size,
                              hipStream_t stream)
{
    const float* x      = (const float*)d_in[0];
    const float* boxes  = (const float*)d_in[1];
    const float* scores = (const float*)d_in[2];
    const float* w1     = (const float*)d_in[3];
    const float* b1     = (const float*)d_in[4];
    const float* w2     = (const float*)d_in[5];
    const float* b2     = (const float*)d_in[6];
    float* out = (float*)d_out;

    // ws layout: h1 slice (8 batches NHWC bf16, 51.38 MB) | w2bf (147 KB) | partial (12.85 MB)
    unsigned short* h1    = (unsigned short*)d_ws;
    unsigned short* w2bf  = (unsigned short*)((char*)d_ws + (size_t)8 * 224 * 224 * 64 * 2);
    float*          partial = (float*)((char*)d_ws + (size_t)8 * 224 * 224 * 64 * 2 + 9 * 128 * 64 * 2);

    w2_convert<<<(9 * 128 * 64 + 255) / 256, 256, 0, stream>>>(w2, w2bf);

    for (int s = 0; s < 4; s++) {
        const float* xs = x + (size_t)s * 8 * 3 * HH * WW;
        conv1_kernel<<<dim3(14, 14, 8), 256, 0, stream>>>(xs, w1, b1, h1);
        conv2_kernel<<<dim3(14, 56, 8), 256, 0, stream>>>(h1, w2bf, b2, partial, s * 8);
    }

    feats_reduce<<<4096, 64, 0, stream>>>(partial, out + OUT_FEATS);
    nms_kernel<<<32, 128, 0, stream>>>(boxes, scores, out);
}

// Round 3
// 480.798 us; speedup vs baseline: 9.5314x; 1.3914x over previous
//
#include <hip/hip_runtime.h>
#include <hip/hip_bf16.h>

#define HH 224
#define WW 224

// d_out layout (floats): feats[32*128] | final_boxes[32*100*4] | final_scores[32*100] | keep[32*100]
#define OUT_FEATS  0
#define OUT_BOXES  4096
#define OUT_SCORES 16896
#define OUT_KEEP   20096

typedef __attribute__((ext_vector_type(8))) short short8;
typedef __attribute__((ext_vector_type(4))) float f32x4;
typedef __attribute__((ext_vector_type(4))) unsigned int u32x4;

static __device__ __forceinline__ unsigned short f2bf(float f) {
    __hip_bfloat16 h = __float2bfloat16(f);
    return *(unsigned short*)&h;
}

static __device__ __forceinline__ void gload_lds16(const void* g, void* l) {
    __builtin_amdgcn_global_load_lds(
        (const __attribute__((address_space(1))) unsigned int*)g,
        (__attribute__((address_space(3))) unsigned int*)l, 16, 0, 0);
}

// ---------------- w2 (128,64,3,3) fp32 -> bf16 [tap][oc][ic] ----------------
__global__ void w2_convert(const float* __restrict__ w2, unsigned short* __restrict__ w2bf)
{
    int t = blockIdx.x * 256 + threadIdx.x;
    if (t >= 9 * 128 * 64) return;
    int tap = t >> 13;
    int rem = t & 8191;
    int oc = rem >> 6, ic = rem & 63;
    w2bf[t] = f2bf(w2[(oc * 64 + ic) * 9 + tap]);
}

// ---------------- conv1: (8,3,224,224) fp32 -> relu -> h1 slice NHWC bf16 ----------------
__global__ __launch_bounds__(256) void conv1_kernel(const float* __restrict__ x,
                                                    const float* __restrict__ w1,
                                                    const float* __restrict__ b1,
                                                    unsigned short* __restrict__ h1)
{
    const int tx = threadIdx.x & 15, ty = threadIdx.x >> 4;
    const int x0 = blockIdx.x * 16, y0 = blockIdx.y * 16, b = blockIdx.z;

    __shared__ float patch[3 * 18 * 18];
    for (int e = threadIdx.x; e < 3 * 18 * 18; e += 256) {
        int ic = e / 324; int rem = e - ic * 324;
        int r = rem / 18; int c = rem - r * 18;
        int gy = y0 + r - 1, gx = x0 + c - 1;
        float v = 0.f;
        if (gy >= 0 && gy < HH && gx >= 0 && gx < WW)
            v = x[((b * 3 + ic) * HH + gy) * WW + gx];
        patch[e] = v;
    }
    __syncthreads();

    float in[27];
#pragma unroll
    for (int ic = 0; ic < 3; ic++)
#pragma unroll
        for (int r = 0; r < 3; r++)
#pragma unroll
            for (int c = 0; c < 3; c++)
                in[ic * 9 + r * 3 + c] = patch[(ic * 18 + ty + r) * 18 + tx + c];

    const int out_y = y0 + ty, out_x = x0 + tx;
    unsigned short* dst = h1 + (((size_t)b * HH + out_y) * WW + out_x) * 64;

#pragma unroll
    for (int g = 0; g < 8; g++) {
        float a[8];
#pragma unroll
        for (int o = 0; o < 8; o++) {
            int oc = g * 8 + o;
            float acc = b1[oc];
#pragma unroll
            for (int k = 0; k < 27; k++) acc = fmaf(in[k], w1[oc * 27 + k], acc);
            a[o] = fmaxf(acc, 0.f);
        }
        u32x4 pk;
        pk.x = (unsigned int)f2bf(a[0]) | ((unsigned int)f2bf(a[1]) << 16);
        pk.y = (unsigned int)f2bf(a[2]) | ((unsigned int)f2bf(a[3]) << 16);
        pk.z = (unsigned int)f2bf(a[4]) | ((unsigned int)f2bf(a[5]) << 16);
        pk.w = (unsigned int)f2bf(a[6]) | ((unsigned int)f2bf(a[7]) << 16);
        *(u32x4*)(dst + g * 8) = pk;
    }
}

// ---------------- conv2 MFMA implicit GEMM + fused relu/mean partials ----------------
// block: 256 thr = 4 waves. Tile: 256 px (16x16 spatial) x 128 oc.
// wave (wm,wn): px rows [wm*8, wm*8+8) x 16 cols = 128 px (M=8), oc [wn*64, +64) (N=4).
// K = 9 taps x 64 ic; per-tap weights double-buffered in LDS via global_load_lds.
// grid: (14 xt, 14 yt, 8 b_local)
__global__ __launch_bounds__(256, 2) void conv2_kernel(const unsigned short* __restrict__ h1,
                                                       const unsigned short* __restrict__ w2bf,
                                                       const float* __restrict__ b2,
                                                       float* __restrict__ partial,
                                                       int bglobal_base)
{
    const int xt = blockIdx.x, yt = blockIdx.y, bl = blockIdx.z;
    const int x0 = xt * 16, y0 = yt * 16;
    const int tid = threadIdx.x;
    const int w = tid >> 6, lane = tid & 63;
    const int wm = w >> 1, wn = w & 1;
    const int l15 = lane & 15, lq = lane >> 4;

    __shared__ short halo[324 * 64];       // 18x18 pos x 64 ic, XOR-swizzled, 41472 B
    __shared__ short wlds[2][128 * 64];    // per-tap weights dbuf, XOR-swizzled, 2x16384 B

    const unsigned short* hb = h1 + (size_t)bl * HH * WW * 64;

    // stage B[tap 0] (async, pre-swizzled source -> linear LDS dest)
#pragma unroll
    for (int it = 0; it < 4; ++it) {
        int cbase = it * 256 + w * 64;
        int c = cbase + lane;
        int src = (c * 16) ^ (((c >> 3) & 7) << 4);
        gload_lds16((const char*)w2bf + src, (char*)&wlds[0][0] + cbase * 16);
    }

    // stage halo (reg-staged, swizzled ds_write; zero-padded borders)
    for (int i = tid; i < 2592; i += 256) {
        int pos = i >> 3, q = i & 7;
        int row = pos / 18, col = pos - row * 18;
        int gy = y0 + row - 1, gx = x0 + col - 1;
        u32x4 v = {0, 0, 0, 0};
        if (gy >= 0 && gy < HH && gx >= 0 && gx < WW)
            v = *(const u32x4*)(hb + ((gy * WW + gx) * 64 + q * 8));
        int byte = (pos * 128 + q * 16) ^ ((pos & 7) << 4);
        *(u32x4*)((char*)halo + byte) = v;
    }
    __syncthreads();

    f32x4 acc[8][4];
#pragma unroll
    for (int mf = 0; mf < 8; mf++)
#pragma unroll
        for (int nf = 0; nf < 4; nf++)
            acc[mf][nf] = (f32x4){0.f, 0.f, 0.f, 0.f};

#pragma unroll
    for (int t = 0; t < 9; ++t) {
        // prefetch next tap's weights into the other LDS buffer
        if (t < 8) {
#pragma unroll
            for (int it = 0; it < 4; ++it) {
                int cbase = it * 256 + w * 64;
                int c = cbase + lane;
                int src = (c * 16) ^ (((c >> 3) & 7) << 4);
                gload_lds16((const char*)w2bf + (t + 1) * 16384 + src,
                            (char*)&wlds[(t + 1) & 1][0] + cbase * 16);
            }
        }
        const int dy = t / 3, dx = t % 3;
        const char* wbuf = (const char*)&wlds[t & 1][0];

#pragma unroll
        for (int kk = 0; kk < 2; kk++) {
            short8 bfr[4];
#pragma unroll
            for (int nf = 0; nf < 4; nf++) {
                int oc = wn * 64 + nf * 16 + l15;
                int byte = (oc * 128 + kk * 64 + lq * 16) ^ ((oc & 7) << 4);
                bfr[nf] = *(const short8*)(wbuf + byte);
            }
            short8 a[8];
#pragma unroll
            for (int mf = 0; mf < 8; mf++) {
                int pos = (wm * 8 + mf + dy) * 18 + (l15 + dx);
                int byte = (pos * 128 + kk * 64 + lq * 16) ^ ((pos & 7) << 4);
                a[mf] = *(const short8*)((const char*)halo + byte);
            }
#pragma unroll
            for (int mf = 0; mf < 8; mf++)
#pragma unroll
                for (int nf = 0; nf < 4; nf++)
                    acc[mf][nf] = __builtin_amdgcn_mfma_f32_16x16x32_bf16(a[mf], bfr[nf], acc[mf][nf], 0, 0, 0);
        }
        __syncthreads();   // drains stage(t+1) vmcnt; publishes wlds[(t+1)&1]
    }

    // epilogue: bias + relu + sum over wave's 128 px; C: col(oc)=l15, row(px)=lq*4+j
    float s[4];
#pragma unroll
    for (int nf = 0; nf < 4; nf++) {
        float bias = b2[wn * 64 + nf * 16 + l15];
        float v = 0.f;
#pragma unroll
        for (int mf = 0; mf < 8; mf++)
#pragma unroll
            for (int j = 0; j < 4; j++)
                v += fmaxf(acc[mf][nf][j] + bias, 0.f);
        v += __shfl_xor(v, 16, 64);
        v += __shfl_xor(v, 32, 64);
        s[nf] = v;
    }

    float* red = (float*)halo;   // reuse; all halo reads done (post final barrier)
    if (lq == 0) {
#pragma unroll
        for (int nf = 0; nf < 4; nf++)
            red[((wm * 2 + wn) * 4 + nf) * 16 + l15] = s[nf];
    }
    __syncthreads();
    if (tid < 128) {
        int oc = tid;
        int wn2 = oc >> 6, nf2 = (oc >> 4) & 3, c16 = oc & 15;
        float tot = red[((0 * 2 + wn2) * 4 + nf2) * 16 + c16] +
                    red[((1 * 2 + wn2) * 4 + nf2) * 16 + c16];
        int bg = bglobal_base + bl;
        int tile = yt * 14 + xt;
        partial[((size_t)bg * 128 + oc) * 196 + tile] = tot;
    }
}

// ---------------- feats: sum 196 tile-partials -> mean ----------------
__global__ void feats_reduce(const float* __restrict__ partial, float* __restrict__ out)
{
    int t = blockIdx.x;           // 0..4095 = b*128+oc
    int lane = threadIdx.x;       // 64
    float s = 0.f;
    for (int k = lane; k < 196; k += 64) s += partial[(size_t)t * 196 + k];
#pragma unroll
    for (int m = 32; m >= 1; m >>= 1) s += __shfl_xor(s, m, 64);
    if (lane == 0) out[t] = s * (1.f / 50176.f);
}

// ---------------- NMS: one block per batch (exact reference semantics) ----------------
__global__ __launch_bounds__(128) void nms_kernel(const float* __restrict__ boxes,
                                                  const float* __restrict__ scores,
                                                  float* __restrict__ out)
{
    const int b = blockIdx.x;
    const int tid = threadIdx.x;
    __shared__ float rs[100];
    __shared__ float bx1[100], by1[100], bx2[100], by2[100];
    __shared__ float ss[100], sx1[100], sy1[100], sx2[100], sy2[100], sarea[100];
    __shared__ int keep_s[100];

    if (tid < 100) {
        rs[tid] = scores[b * 100 + tid];
        bx1[tid] = boxes[(b * 100 + tid) * 4 + 0];
        by1[tid] = boxes[(b * 100 + tid) * 4 + 1];
        bx2[tid] = boxes[(b * 100 + tid) * 4 + 2];
        by2[tid] = boxes[(b * 100 + tid) * 4 + 3];
    }
    __syncthreads();
    if (tid < 100) {
        float s = rs[tid];
        int r = 0;
        for (int j = 0; j < 100; j++) {
            float sj = rs[j];
            r += (sj > s) || (sj == s && j < tid);  // stable descending rank
        }
        ss[r] = s; sx1[r] = bx1[tid]; sy1[r] = by1[tid];
        sx2[r] = bx2[tid]; sy2[r] = by2[tid];
        keep_s[tid] = 1;
    }
    __syncthreads();
    if (tid < 100)
        sarea[tid] = fmaxf(sx2[tid] - sx1[tid], 0.f) * fmaxf(sy2[tid] - sy1[tid], 0.f);
    __syncthreads();

    for (int i = 0; i < 99; i++) {
        if (keep_s[i] && tid > i && tid < 100) {
            float xx1 = fmaxf(sx1[i], sx1[tid]);
            float yy1 = fmaxf(sy1[i], sy1[tid]);
            float xx2 = fminf(sx2[i], sx2[tid]);
            float yy2 = fminf(sy2[i], sy2[tid]);
            float inter = fmaxf(xx2 - xx1, 0.f) * fmaxf(yy2 - yy1, 0.f);
            float iou = inter / (sarea[i] + sarea[tid] - inter + 1e-9f);
            if (iou > 0.5f) keep_s[tid] = 0;
        }
        __syncthreads();
    }

    if (tid < 100) {
        int k = keep_s[tid];
        int gi = b * 100 + tid;
        out[OUT_BOXES + gi * 4 + 0] = k ? sx1[tid] : 0.f;
        out[OUT_BOXES + gi * 4 + 1] = k ? sy1[tid] : 0.f;
        out[OUT_BOXES + gi * 4 + 2] = k ? sx2[tid] : 0.f;
        out[OUT_BOXES + gi * 4 + 3] = k ? sy2[tid] : 0.f;
        out[OUT_SCORES + gi] = k ? ss[tid] : 0.f;
        out[OUT_KEEP + gi] = k ? 1.f : 0.f;
    }
}

extern "C" void kernel_launch(void* const* d_in, const int* in_sizes, int n_in,
                              void* d_out, int out_size, void* d_ws, size_t ws_size,
                              hipStream_t stream)
{
    const float* x      = (const float*)d_in[0];
    const float* boxes  = (const float*)d_in[1];
    const float* scores = (const float*)d_in[2];
    const float* w1     = (const float*)d_in[3];
    const float* b1     = (const float*)d_in[4];
    const float* w2     = (const float*)d_in[5];
    const float* b2     = (const float*)d_in[6];
    float* out = (float*)d_out;

    // ws: h1 slice (8 batches NHWC bf16, 51.38 MB) | w2bf (147 KB) | partial (3.2 MB)
    unsigned short* h1    = (unsigned short*)d_ws;
    unsigned short* w2bf  = (unsigned short*)((char*)d_ws + (size_t)8 * 224 * 224 * 64 * 2);
    float*          partial = (float*)((char*)d_ws + (size_t)8 * 224 * 224 * 64 * 2 + 9 * 128 * 64 * 2);

    w2_convert<<<(9 * 128 * 64 + 255) / 256, 256, 0, stream>>>(w2, w2bf);

    for (int s = 0; s < 4; s++) {
        const float* xs = x + (size_t)s * 8 * 3 * HH * WW;
        conv1_kernel<<<dim3(14, 14, 8), 256, 0, stream>>>(xs, w1, b1, h1);
        conv2_kernel<<<dim3(14, 14, 8), 256, 0, stream>>>(h1, w2bf, b2, partial, s * 8);
    }

    feats_reduce<<<4096, 64, 0, stream>>>(partial, out + OUT_FEATS);
    nms_kernel<<<32, 128, 0, stream>>>(boxes, scores, out);
}